// Round 5
// baseline (807.056 us; speedup 1.0000x reference)
//
#include <hip/hip_runtime.h>
#include <hip/hip_bf16.h>
#include <math.h>

// ROUND 5 = MEASUREMENT PROBE. ll_kernel is byte-identical to round 4;
// it is launched 3x (idempotent) so dur_us_r5 - dur_us_r4 = 2 * t_ll.

#define NP 100000
#define KC 64
#define OD 1024
#define EPSF 1e-6f

#define ROWS_PER_BLOCK 128
#define NBLOCKS ((NP + ROWS_PER_BLOCK - 1) / ROWS_PER_BLOCK)  // 782

typedef __attribute__((ext_vector_type(8))) short short8;
typedef __attribute__((ext_vector_type(4))) float f32x4;

#define WS_LOGW      0
#define WS_PARTIALS  256
#define WS_BSTAGE    8192

__device__ __forceinline__ unsigned short f32_bf16_rn(float f) {
  unsigned int u = __float_as_uint(f);
  unsigned int r = u + 0x7fffu + ((u >> 16) & 1u);
  return (unsigned short)(r >> 16);
}

__global__ void prep_kernel(const float* __restrict__ otu,
                            const float* __restrict__ comm,
                            unsigned short* __restrict__ bstage,
                            float* __restrict__ logw) {
  int b = blockIdx.x;
  if (b < KC) {
    int c = b & 15, ct = b >> 4;
    for (int k = threadIdx.x; k < OD; k += blockDim.x) {
      float x = logf(otu[b * OD + k] + EPSF);
      unsigned short h = f32_bf16_rn(x);
      float hf = __uint_as_float(((unsigned int)h) << 16);
      unsigned short l = f32_bf16_rn(x - hf);
      int kb = k >> 5, g = (k >> 3) & 3, kk = k & 7;
      size_t base = (size_t)kb * 4096 + (size_t)ct * 512
                  + (size_t)(g * 16 + c) * 8 + kk;
      bstage[base] = h;           // hi (h=0)
      bstage[base + 2048] = l;    // lo (h=1)
    }
  } else {
    if (threadIdx.x < KC) logw[threadIdx.x] = logf(comm[threadIdx.x] + EPSF);
  }
}

__global__ __launch_bounds__(256, 2)
void ll_kernel(const float* __restrict__ counts,
               const unsigned short* __restrict__ bstage,
               const float* __restrict__ logw,
               double* __restrict__ partials) {
  const int tid = threadIdx.x;
  const int wave = tid >> 6;
  const int lane = tid & 63;
  const int g = lane >> 4;   // k-group within frag
  const int c = lane & 15;   // A-row / B-col within 16-tile
  const int rowBase = blockIdx.x * ROWS_PER_BLOCK + wave * 32;

  f32x4 acc[2][4];
#pragma unroll
  for (int i = 0; i < 2; ++i)
#pragma unroll
    for (int j = 0; j < 4; ++j)
      acc[i][j] = (f32x4){0.f, 0.f, 0.f, 0.f};

  int r0 = rowBase + c;      if (r0 >= NP) r0 = NP - 1;  // tail rows dropped in epilogue
  int r1 = rowBase + 16 + c; if (r1 >= NP) r1 = NP - 1;
  const float* pa0 = counts + (size_t)r0 * OD + g * 8;
  const float* pa1 = counts + (size_t)r1 * OD + g * 8;

  const int p = blockIdx.x & 3;   // chunk-phase rotation

  for (int ci = 0; ci < 4; ++ci) {
    const int t = (p + ci) & 3;            // K-chunk: cols [t*256, t*256+256)
    const float* a0 = pa0 + t * 256;
    const float* a1 = pa1 + t * 256;

    // 1) burst-issue all 32 A loads (1 KB contiguous per row per visit)
    float4 x0[8], x1[8], y0[8], y1[8];
#pragma unroll
    for (int s = 0; s < 8; ++s) {
      x0[s] = *(const float4*)(a0 + s * 32);
      x1[s] = *(const float4*)(a0 + s * 32 + 4);
      y0[s] = *(const float4*)(a1 + s * 32);
      y1[s] = *(const float4*)(a1 + s * 32 + 4);
    }

    // 2) pack to bf16 (truncation; exact for integer counts)
    short8 ah0[8], ah1[8];
#pragma unroll
    for (int s = 0; s < 8; ++s) {
      union { unsigned int u[4]; short8 v; } u0, u1;
      u0.u[0] = __builtin_amdgcn_perm(__float_as_uint(x0[s].y), __float_as_uint(x0[s].x), 0x07060302u);
      u0.u[1] = __builtin_amdgcn_perm(__float_as_uint(x0[s].w), __float_as_uint(x0[s].z), 0x07060302u);
      u0.u[2] = __builtin_amdgcn_perm(__float_as_uint(x1[s].y), __float_as_uint(x1[s].x), 0x07060302u);
      u0.u[3] = __builtin_amdgcn_perm(__float_as_uint(x1[s].w), __float_as_uint(x1[s].z), 0x07060302u);
      u1.u[0] = __builtin_amdgcn_perm(__float_as_uint(y0[s].y), __float_as_uint(y0[s].x), 0x07060302u);
      u1.u[1] = __builtin_amdgcn_perm(__float_as_uint(y0[s].w), __float_as_uint(y0[s].z), 0x07060302u);
      u1.u[2] = __builtin_amdgcn_perm(__float_as_uint(y1[s].y), __float_as_uint(y1[s].x), 0x07060302u);
      u1.u[3] = __builtin_amdgcn_perm(__float_as_uint(y1[s].w), __float_as_uint(y1[s].z), 0x07060302u);
      ah0[s] = u0.v;
      ah1[s] = u1.v;
    }

    // 3) compute: per 32-k sub-step, B frags from L2 + 16 MFMA
#pragma unroll
    for (int s = 0; s < 8; ++s) {
      const int kb = t * 8 + s;
      const unsigned short* bb = bstage + (size_t)kb * 4096 + (size_t)lane * 8;
      short8 fbh[4], fbl[4];
#pragma unroll
      for (int ct = 0; ct < 4; ++ct) {
        fbh[ct] = *(const short8*)(bb + ct * 512);
        fbl[ct] = *(const short8*)(bb + 2048 + ct * 512);
      }
#pragma unroll
      for (int ct = 0; ct < 4; ++ct) {
        acc[0][ct] = __builtin_amdgcn_mfma_f32_16x16x32_bf16(ah0[s], fbh[ct], acc[0][ct], 0, 0, 0);
        acc[1][ct] = __builtin_amdgcn_mfma_f32_16x16x32_bf16(ah1[s], fbh[ct], acc[1][ct], 0, 0, 0);
        acc[0][ct] = __builtin_amdgcn_mfma_f32_16x16x32_bf16(ah0[s], fbl[ct], acc[0][ct], 0, 0, 0);
        acc[1][ct] = __builtin_amdgcn_mfma_f32_16x16x32_bf16(ah1[s], fbl[ct], acc[1][ct], 0, 0, 0);
      }
    }
  }

  // ---- epilogue: + logw, logsumexp over 64 cols per row, accumulate rows ----
  float lw[4];
#pragma unroll
  for (int ct = 0; ct < 4; ++ct) lw[ct] = logw[ct * 16 + c];

  double lsum = 0.0;
#pragma unroll
  for (int rt = 0; rt < 2; ++rt) {
#pragma unroll
    for (int r = 0; r < 4; ++r) {
      float v0 = acc[rt][0][r] + lw[0];
      float v1 = acc[rt][1][r] + lw[1];
      float v2 = acc[rt][2][r] + lw[2];
      float v3 = acc[rt][3][r] + lw[3];
      float m = fmaxf(fmaxf(v0, v1), fmaxf(v2, v3));
      m = fmaxf(m, __shfl_xor(m, 1));
      m = fmaxf(m, __shfl_xor(m, 2));
      m = fmaxf(m, __shfl_xor(m, 4));
      m = fmaxf(m, __shfl_xor(m, 8));
      float s = __expf(v0 - m) + __expf(v1 - m) + __expf(v2 - m) + __expf(v3 - m);
      s += __shfl_xor(s, 1);
      s += __shfl_xor(s, 2);
      s += __shfl_xor(s, 4);
      s += __shfl_xor(s, 8);
      float lse = m + __logf(s);
      int row = rowBase + rt * 16 + g * 4 + r;
      if (c == 0 && row < NP) lsum += (double)lse;
    }
  }
  lsum += __shfl_xor(lsum, 16);
  lsum += __shfl_xor(lsum, 32);

  __shared__ double wpart[4];
  if (lane == 0) wpart[wave] = lsum;
  __syncthreads();
  if (tid == 0) partials[blockIdx.x] = wpart[0] + wpart[1] + wpart[2] + wpart[3];
}

__global__ void finalize_kernel(const double* __restrict__ partials,
                                float* __restrict__ out) {
  double s = 0.0;
  for (int i = threadIdx.x; i < NBLOCKS; i += 256) s += partials[i];
  s += __shfl_xor(s, 1);
  s += __shfl_xor(s, 2);
  s += __shfl_xor(s, 4);
  s += __shfl_xor(s, 8);
  s += __shfl_xor(s, 16);
  s += __shfl_xor(s, 32);
  __shared__ double sp[4];
  int w = threadIdx.x >> 6, lane = threadIdx.x & 63;
  if (lane == 0) sp[w] = s;
  __syncthreads();
  if (threadIdx.x == 0) out[0] = (float)(sp[0] + sp[1] + sp[2] + sp[3]);
}

extern "C" void kernel_launch(void* const* d_in, const int* in_sizes, int n_in,
                              void* d_out, int out_size, void* d_ws, size_t ws_size,
                              hipStream_t stream) {
  const float* counts = (const float*)d_in[0];
  const float* otu    = (const float*)d_in[1];
  const float* comm   = (const float*)d_in[2];
  float* out = (float*)d_out;
  char* ws = (char*)d_ws;

  float* logw          = (float*)(ws + WS_LOGW);
  double* partials     = (double*)(ws + WS_PARTIALS);
  unsigned short* bst  = (unsigned short*)(ws + WS_BSTAGE);

  prep_kernel<<<KC + 1, 256, 0, stream>>>(otu, comm, bst, logw);
  // Probe: 3 identical idempotent launches; dur_r5 - dur_r4 = 2 * t_ll.
  ll_kernel<<<NBLOCKS, 256, 0, stream>>>(counts, bst, logw, partials);
  ll_kernel<<<NBLOCKS, 256, 0, stream>>>(counts, bst, logw, partials);
  ll_kernel<<<NBLOCKS, 256, 0, stream>>>(counts, bst, logw, partials);
  finalize_kernel<<<1, 256, 0, stream>>>(partials, out);
}

// Round 6
// 608.222 us; speedup vs baseline: 1.3269x; 1.3269x over previous
//
#include <hip/hip_runtime.h>
#include <hip/hip_bf16.h>
#include <math.h>

#define NP 100000
#define KC 64
#define OD 1024
#define EPSF 1e-6f

#define ROWS_PER_BLOCK 32
#define NBLK 3125           // 3125 * 32 = 100000 exactly (no tail)

typedef __attribute__((ext_vector_type(8))) short short8;
typedef __attribute__((ext_vector_type(4))) float f32x4;

// ---- ws layout ----
// [0     .. 256)    : logw (64 floats)
// [256   .. 25256)  : per-block double partials (NBLK * 8)
// [32768 .. +256K)  : bstage, frag-ordered B (identical to rounds 4/5):
//                     short idx = kb*4096 + ct*512 + (g*16+c)*8 + kk  (hi)
//                                 +2048 within kb-block               (lo)
#define WS_LOGW      0
#define WS_PARTIALS  256
#define WS_BSTAGE    32768

__device__ __forceinline__ unsigned short f32_bf16_rn(float f) {
  unsigned int u = __float_as_uint(f);
  unsigned int r = u + 0x7fffu + ((u >> 16) & 1u);
  return (unsigned short)(r >> 16);
}

__global__ void prep_kernel(const float* __restrict__ otu,
                            const float* __restrict__ comm,
                            unsigned short* __restrict__ bstage,
                            float* __restrict__ logw) {
  int b = blockIdx.x;
  if (b < KC) {
    int c = b & 15, ct = b >> 4;
    for (int k = threadIdx.x; k < OD; k += blockDim.x) {
      float x = logf(otu[b * OD + k] + EPSF);
      unsigned short h = f32_bf16_rn(x);
      float hf = __uint_as_float(((unsigned int)h) << 16);
      unsigned short l = f32_bf16_rn(x - hf);
      int kb = k >> 5, g = (k >> 3) & 3, kk = k & 7;
      size_t base = (size_t)kb * 4096 + (size_t)ct * 512
                  + (size_t)(g * 16 + c) * 8 + kk;
      bstage[base] = h;           // hi
      bstage[base + 2048] = l;    // lo
    }
  } else {
    if (threadIdx.x < KC) logw[threadIdx.x] = logf(comm[threadIdx.x] + EPSF);
  }
}

// One wave per block, 32 rows, full K in two 512-col halves.
// KEY CHANGE vs rounds 1-5: every global A load is 1 KB CONTIGUOUS WITHIN ONE
// ROW (64 lanes x float4), rows walked in order -> DRAM sees sequential 2 KB
// page-aligned bursts instead of interleaved 128 B granules from 32 streams.
// The lane->fragment transpose goes through a 32 KB LDS buffer:
//   layout byte = klocal*2048 + rt*1024 + g*256 + c*16 + h*8, XOR ((klocal&7)<<4)
// (write: 64 lanes x 8B dense, read: b128 dense; both conflict-free).
// B frags come straight from L2-resident bstage as in round 4. No barriers.
__global__ __launch_bounds__(64)
void ll_kernel(const float* __restrict__ counts,
               const unsigned short* __restrict__ bstage,
               const float* __restrict__ logw,
               double* __restrict__ partials) {
  __shared__ unsigned short afrag[16384];   // 32 KB
  char* lds = (char*)afrag;
  const int lane = threadIdx.x;
  const int g = lane >> 4, c = lane & 15;
  const int row0 = blockIdx.x * ROWS_PER_BLOCK;
  const float* src = counts + (size_t)row0 * OD;

  // staging lane constants: lane l packs cols q2*256 + l*4 .. +3 of each row
  const int kb3 = lane >> 3;          // klocal & 7
  const int gq  = (lane >> 1) & 3;
  const int hq  = lane & 1;
  const int cA0 = kb3 * 2048 + gq * 256 + hq * 8;   // q2 = 0 (klocal = kb3)
  const int cA1 = 16384 + cA0;                      // q2 = 1 (klocal = 8+kb3)

  f32x4 acc[2][4];
#pragma unroll
  for (int i = 0; i < 2; ++i)
#pragma unroll
    for (int j = 0; j < 4; ++j)
      acc[i][j] = (f32x4){0.f, 0.f, 0.f, 0.f};

  for (int hf = 0; hf < 2; ++hf) {
    const float* hsrc = src + hf * 512 + lane * 4;

    // ---- stage: 32 rows x 2KB (this K-half), row-sequential reads ----
    float4 fb[4][2];
#pragma unroll
    for (int r = 0; r < 4; ++r) {
      fb[r][0] = *(const float4*)(hsrc + r * 1024);
      fb[r][1] = *(const float4*)(hsrc + r * 1024 + 256);
    }
#pragma unroll
    for (int r = 0; r < 32; ++r) {
      const int slot = r & 3;
      const int roff = ((r >> 4) << 10) + (((r & 15) ^ kb3) << 4);
      {
        float4 f = fb[slot][0];
        uint2 w;
        w.x = __builtin_amdgcn_perm(__float_as_uint(f.y), __float_as_uint(f.x), 0x07060302u);
        w.y = __builtin_amdgcn_perm(__float_as_uint(f.w), __float_as_uint(f.z), 0x07060302u);
        *(uint2*)(lds + cA0 + roff) = w;
        f = fb[slot][1];
        w.x = __builtin_amdgcn_perm(__float_as_uint(f.y), __float_as_uint(f.x), 0x07060302u);
        w.y = __builtin_amdgcn_perm(__float_as_uint(f.w), __float_as_uint(f.z), 0x07060302u);
        *(uint2*)(lds + cA1 + roff) = w;
      }
      if (r + 4 < 32) {
        fb[slot][0] = *(const float4*)(hsrc + (r + 4) * 1024);
        fb[slot][1] = *(const float4*)(hsrc + (r + 4) * 1024 + 256);
      }
    }

    // ---- consume: 16 k-steps of this half (global kb = hf*16 + kl) ----
#pragma unroll
    for (int kl = 0; kl < 16; ++kl) {
      const int swz = (c ^ (kl & 7)) << 4;
      short8 a0 = *(const short8*)(lds + kl * 2048 + g * 256 + swz);
      short8 a1 = *(const short8*)(lds + kl * 2048 + 1024 + g * 256 + swz);
      const unsigned short* bb = bstage + (size_t)(hf * 16 + kl) * 4096 + lane * 8;
      short8 bh[4], bl[4];
#pragma unroll
      for (int ct = 0; ct < 4; ++ct) {
        bh[ct] = *(const short8*)(bb + ct * 512);
        bl[ct] = *(const short8*)(bb + 2048 + ct * 512);
      }
#pragma unroll
      for (int ct = 0; ct < 4; ++ct) {
        acc[0][ct] = __builtin_amdgcn_mfma_f32_16x16x32_bf16(a0, bh[ct], acc[0][ct], 0, 0, 0);
        acc[1][ct] = __builtin_amdgcn_mfma_f32_16x16x32_bf16(a1, bh[ct], acc[1][ct], 0, 0, 0);
        acc[0][ct] = __builtin_amdgcn_mfma_f32_16x16x32_bf16(a0, bl[ct], acc[0][ct], 0, 0, 0);
        acc[1][ct] = __builtin_amdgcn_mfma_f32_16x16x32_bf16(a1, bl[ct], acc[1][ct], 0, 0, 0);
      }
    }
  }

  // ---- epilogue: + logw, logsumexp over 64 cols per row, accumulate rows ----
  float lw[4];
#pragma unroll
  for (int ct = 0; ct < 4; ++ct) lw[ct] = logw[ct * 16 + c];

  double lsum = 0.0;
#pragma unroll
  for (int rt = 0; rt < 2; ++rt) {
#pragma unroll
    for (int r = 0; r < 4; ++r) {
      // lane holds cols {ct*16+c}, row = row0 + rt*16 + g*4 + r (always < NP)
      float v0 = acc[rt][0][r] + lw[0];
      float v1 = acc[rt][1][r] + lw[1];
      float v2 = acc[rt][2][r] + lw[2];
      float v3 = acc[rt][3][r] + lw[3];
      float m = fmaxf(fmaxf(v0, v1), fmaxf(v2, v3));
      m = fmaxf(m, __shfl_xor(m, 1));
      m = fmaxf(m, __shfl_xor(m, 2));
      m = fmaxf(m, __shfl_xor(m, 4));
      m = fmaxf(m, __shfl_xor(m, 8));
      float s = __expf(v0 - m) + __expf(v1 - m) + __expf(v2 - m) + __expf(v3 - m);
      s += __shfl_xor(s, 1);
      s += __shfl_xor(s, 2);
      s += __shfl_xor(s, 4);
      s += __shfl_xor(s, 8);
      float lse = m + __logf(s);
      if (c == 0) lsum += (double)lse;
    }
  }
  lsum += __shfl_xor(lsum, 16);
  lsum += __shfl_xor(lsum, 32);
  if (lane == 0) partials[blockIdx.x] = lsum;
}

__global__ void finalize_kernel(const double* __restrict__ partials,
                                float* __restrict__ out) {
  double s = 0.0;
  for (int i = threadIdx.x; i < NBLK; i += 256) s += partials[i];
  s += __shfl_xor(s, 1);
  s += __shfl_xor(s, 2);
  s += __shfl_xor(s, 4);
  s += __shfl_xor(s, 8);
  s += __shfl_xor(s, 16);
  s += __shfl_xor(s, 32);
  __shared__ double sp[4];
  int w = threadIdx.x >> 6, lane = threadIdx.x & 63;
  if (lane == 0) sp[w] = s;
  __syncthreads();
  if (threadIdx.x == 0) out[0] = (float)(sp[0] + sp[1] + sp[2] + sp[3]);
}

extern "C" void kernel_launch(void* const* d_in, const int* in_sizes, int n_in,
                              void* d_out, int out_size, void* d_ws, size_t ws_size,
                              hipStream_t stream) {
  const float* counts = (const float*)d_in[0];
  const float* otu    = (const float*)d_in[1];
  const float* comm   = (const float*)d_in[2];
  float* out = (float*)d_out;
  char* ws = (char*)d_ws;

  float* logw          = (float*)(ws + WS_LOGW);
  double* partials     = (double*)(ws + WS_PARTIALS);
  unsigned short* bst  = (unsigned short*)(ws + WS_BSTAGE);

  prep_kernel<<<KC + 1, 256, 0, stream>>>(otu, comm, bst, logw);
  ll_kernel<<<NBLK, 64, 0, stream>>>(counts, bst, logw, partials);
  finalize_kernel<<<1, 256, 0, stream>>>(partials, out);
}

// Round 11
// 583.233 us; speedup vs baseline: 1.3838x; 1.0428x over previous
//
#include <hip/hip_runtime.h>
#include <hip/hip_bf16.h>
#include <math.h>

#define NP 100000
#define KC 64
#define OD 1024
#define EPSF 1e-6f

#define ROWS_PER_BLOCK 128
#define NBLOCKS ((NP + ROWS_PER_BLOCK - 1) / ROWS_PER_BLOCK)  // 782

typedef __attribute__((ext_vector_type(8))) short short8;
typedef __attribute__((ext_vector_type(4))) float f32x4;

// ---- ws layout ----
// [0    .. 256)   : logw, 64 floats
// [256  .. 6512)  : per-block double partials (NBLOCKS * 8)
// [8192 .. +256K) : bstage, frag-ordered B (identical to round 4):
//                   short idx = kb*4096 + ct*512 + (g*16+c)*8 + kk   (hi)
//                               +2048 within kb-block                (lo)
#define WS_LOGW      0
#define WS_PARTIALS  256
#define WS_BSTAGE    8192

__device__ __forceinline__ unsigned short f32_bf16_rn(float f) {
  unsigned int u = __float_as_uint(f);
  unsigned int r = u + 0x7fffu + ((u >> 16) & 1u);
  return (unsigned short)(r >> 16);
}

__global__ void prep_kernel(const float* __restrict__ otu,
                            const float* __restrict__ comm,
                            unsigned short* __restrict__ bstage,
                            float* __restrict__ logw) {
  int b = blockIdx.x;
  if (b < KC) {
    int c = b & 15, ct = b >> 4;
    for (int k = threadIdx.x; k < OD; k += blockDim.x) {
      float x = logf(otu[b * OD + k] + EPSF);
      unsigned short h = f32_bf16_rn(x);
      float hf = __uint_as_float(((unsigned int)h) << 16);
      unsigned short l = f32_bf16_rn(x - hf);
      int kb = k >> 5, g = (k >> 3) & 3, kk = k & 7;
      size_t base = (size_t)kb * 4096 + (size_t)ct * 512
                  + (size_t)(g * 16 + c) * 8 + kk;
      bstage[base] = h;           // hi
      bstage[base + 2048] = l;    // lo
    }
  } else {
    if (threadIdx.x < KC) logw[threadIdx.x] = logf(comm[threadIdx.x] + EPSF);
  }
}

// A-load double-buffer: one 64-col phase (2 k-steps) of 2 row-groups.
// 8 x f32x4 per buffer; nontemporal so streaming counts doesn't evict
// bstage from L2. (ext_vector_type, not HIP float4 — builtin requirement.)
struct AG { f32x4 x0[2], x1[2], y0[2], y1[2]; };

__device__ __forceinline__ void load_group(AG& b, const float* a0, const float* a1) {
#pragma unroll
  for (int s = 0; s < 2; ++s) {
    b.x0[s] = __builtin_nontemporal_load((const f32x4*)(a0 + s * 32));
    b.x1[s] = __builtin_nontemporal_load((const f32x4*)(a0 + s * 32 + 4));
    b.y0[s] = __builtin_nontemporal_load((const f32x4*)(a1 + s * 32));
    b.y1[s] = __builtin_nontemporal_load((const f32x4*)(a1 + s * 32 + 4));
  }
}

__device__ __forceinline__ void compute_group(const AG& b, int ph,
                                              const unsigned short* __restrict__ bstage,
                                              int lane, f32x4 (&acc)[2][4]) {
#pragma unroll
  for (int s = 0; s < 2; ++s) {
    // pack to bf16 (truncation; exact for integer counts)
    union { unsigned int u[4]; short8 v; } u0, u1;
    u0.u[0] = __builtin_amdgcn_perm(__float_as_uint(b.x0[s].y), __float_as_uint(b.x0[s].x), 0x07060302u);
    u0.u[1] = __builtin_amdgcn_perm(__float_as_uint(b.x0[s].w), __float_as_uint(b.x0[s].z), 0x07060302u);
    u0.u[2] = __builtin_amdgcn_perm(__float_as_uint(b.x1[s].y), __float_as_uint(b.x1[s].x), 0x07060302u);
    u0.u[3] = __builtin_amdgcn_perm(__float_as_uint(b.x1[s].w), __float_as_uint(b.x1[s].z), 0x07060302u);
    u1.u[0] = __builtin_amdgcn_perm(__float_as_uint(b.y0[s].y), __float_as_uint(b.y0[s].x), 0x07060302u);
    u1.u[1] = __builtin_amdgcn_perm(__float_as_uint(b.y0[s].w), __float_as_uint(b.y0[s].z), 0x07060302u);
    u1.u[2] = __builtin_amdgcn_perm(__float_as_uint(b.y1[s].y), __float_as_uint(b.y1[s].x), 0x07060302u);
    u1.u[3] = __builtin_amdgcn_perm(__float_as_uint(b.y1[s].w), __float_as_uint(b.y1[s].z), 0x07060302u);

    const int kb = ph * 2 + s;
    const unsigned short* bb = bstage + (size_t)kb * 4096 + (size_t)lane * 8;
    short8 bh[4], bl[4];
#pragma unroll
    for (int ct = 0; ct < 4; ++ct) {
      bh[ct] = *(const short8*)(bb + ct * 512);
      bl[ct] = *(const short8*)(bb + 2048 + ct * 512);
    }
#pragma unroll
    for (int ct = 0; ct < 4; ++ct) {
      acc[0][ct] = __builtin_amdgcn_mfma_f32_16x16x32_bf16(u0.v, bh[ct], acc[0][ct], 0, 0, 0);
      acc[1][ct] = __builtin_amdgcn_mfma_f32_16x16x32_bf16(u1.v, bh[ct], acc[1][ct], 0, 0, 0);
      acc[0][ct] = __builtin_amdgcn_mfma_f32_16x16x32_bf16(u0.v, bl[ct], acc[0][ct], 0, 0, 0);
      acc[1][ct] = __builtin_amdgcn_mfma_f32_16x16x32_bf16(u1.v, bl[ct], acc[1][ct], 0, 0, 0);
    }
  }
}

// Round-4 structure (4 waves x 32 rows, frag-layout A loads, B direct from
// L2-resident bstage, no barriers) + 16-phase register double-buffer so A
// loads are in flight during EVERY compute window (duty-cycle fix), and
// nontemporal A loads (L2-thrash fix).
__global__ __launch_bounds__(256, 2)
void ll_kernel(const float* __restrict__ counts,
               const unsigned short* __restrict__ bstage,
               const float* __restrict__ logw,
               double* __restrict__ partials) {
  const int tid = threadIdx.x;
  const int wave = tid >> 6;
  const int lane = tid & 63;
  const int g = lane >> 4;   // k-group within frag
  const int c = lane & 15;   // A-row / B-col within 16-tile
  const int rowBase = blockIdx.x * ROWS_PER_BLOCK + wave * 32;

  f32x4 acc[2][4];
#pragma unroll
  for (int i = 0; i < 2; ++i)
#pragma unroll
    for (int j = 0; j < 4; ++j)
      acc[i][j] = (f32x4){0.f, 0.f, 0.f, 0.f};

  int r0 = rowBase + c;      if (r0 >= NP) r0 = NP - 1;  // tail rows dropped in epilogue
  int r1 = rowBase + 16 + c; if (r1 >= NP) r1 = NP - 1;
  const float* pa0 = counts + (size_t)r0 * OD + g * 8;
  const float* pa1 = counts + (size_t)r1 * OD + g * 8;

  const int p0 = (blockIdx.x & 7) << 1;   // phase rotation (64-col phases)

  AG bA, bB;
  load_group(bA, pa0 + (size_t)(p0 & 15) * 64, pa1 + (size_t)(p0 & 15) * 64);

#pragma unroll
  for (int i = 0; i < 16; ++i) {
    const int ph  = (p0 + i) & 15;
    const int phn = (p0 + i + 1) & 15;
    if ((i & 1) == 0) {
      if (i < 15) load_group(bB, pa0 + (size_t)phn * 64, pa1 + (size_t)phn * 64);
      compute_group(bA, ph, bstage, lane, acc);
    } else {
      if (i < 15) load_group(bA, pa0 + (size_t)phn * 64, pa1 + (size_t)phn * 64);
      compute_group(bB, ph, bstage, lane, acc);
    }
  }

  // ---- epilogue: + logw, logsumexp over 64 cols per row, accumulate rows ----
  float lw[4];
#pragma unroll
  for (int ct = 0; ct < 4; ++ct) lw[ct] = logw[ct * 16 + c];

  double lsum = 0.0;
#pragma unroll
  for (int rt = 0; rt < 2; ++rt) {
#pragma unroll
    for (int r = 0; r < 4; ++r) {
      // lane holds cols {ct*16+c}, row = rowBase + rt*16 + g*4 + r
      float v0 = acc[rt][0][r] + lw[0];
      float v1 = acc[rt][1][r] + lw[1];
      float v2 = acc[rt][2][r] + lw[2];
      float v3 = acc[rt][3][r] + lw[3];
      float m = fmaxf(fmaxf(v0, v1), fmaxf(v2, v3));
      m = fmaxf(m, __shfl_xor(m, 1));
      m = fmaxf(m, __shfl_xor(m, 2));
      m = fmaxf(m, __shfl_xor(m, 4));
      m = fmaxf(m, __shfl_xor(m, 8));
      float s = __expf(v0 - m) + __expf(v1 - m) + __expf(v2 - m) + __expf(v3 - m);
      s += __shfl_xor(s, 1);
      s += __shfl_xor(s, 2);
      s += __shfl_xor(s, 4);
      s += __shfl_xor(s, 8);
      float lse = m + __logf(s);
      int row = rowBase + rt * 16 + g * 4 + r;
      if (c == 0 && row < NP) lsum += (double)lse;
    }
  }
  lsum += __shfl_xor(lsum, 16);
  lsum += __shfl_xor(lsum, 32);

  __shared__ double wpart[4];
  if (lane == 0) wpart[wave] = lsum;
  __syncthreads();
  if (tid == 0) partials[blockIdx.x] = wpart[0] + wpart[1] + wpart[2] + wpart[3];
}

__global__ void finalize_kernel(const double* __restrict__ partials,
                                float* __restrict__ out) {
  double s = 0.0;
  for (int i = threadIdx.x; i < NBLOCKS; i += 256) s += partials[i];
  s += __shfl_xor(s, 1);
  s += __shfl_xor(s, 2);
  s += __shfl_xor(s, 4);
  s += __shfl_xor(s, 8);
  s += __shfl_xor(s, 16);
  s += __shfl_xor(s, 32);
  __shared__ double sp[4];
  int w = threadIdx.x >> 6, lane = threadIdx.x & 63;
  if (lane == 0) sp[w] = s;
  __syncthreads();
  if (threadIdx.x == 0) out[0] = (float)(sp[0] + sp[1] + sp[2] + sp[3]);
}

extern "C" void kernel_launch(void* const* d_in, const int* in_sizes, int n_in,
                              void* d_out, int out_size, void* d_ws, size_t ws_size,
                              hipStream_t stream) {
  const float* counts = (const float*)d_in[0];
  const float* otu    = (const float*)d_in[1];
  const float* comm   = (const float*)d_in[2];
  float* out = (float*)d_out;
  char* ws = (char*)d_ws;

  float* logw          = (float*)(ws + WS_LOGW);
  double* partials     = (double*)(ws + WS_PARTIALS);
  unsigned short* bst  = (unsigned short*)(ws + WS_BSTAGE);

  prep_kernel<<<KC + 1, 256, 0, stream>>>(otu, comm, bst, logw);
  ll_kernel<<<NBLOCKS, 256, 0, stream>>>(counts, bst, logw, partials);
  finalize_kernel<<<1, 256, 0, stream>>>(partials, out);
}

// Round 12
// 566.946 us; speedup vs baseline: 1.4235x; 1.0287x over previous
//
#include <hip/hip_runtime.h>
#include <hip/hip_bf16.h>
#include <math.h>

// REVERT to round-4 kernel: best measured configuration (564.1 us, absmax 0.0).
// Six schedule variants (LDS K32/K64 staging, reg-burst K256, row-sequential,
// reg-dbuf+nontemporal) all land at t_ll ~120-165 us => memory-system-limited
// at ~3.4 TB/s for this pattern; on-CU pipes <10% busy. This is the endpoint.

#define NP 100000
#define KC 64
#define OD 1024
#define EPSF 1e-6f

#define ROWS_PER_BLOCK 128
#define NBLOCKS ((NP + ROWS_PER_BLOCK - 1) / ROWS_PER_BLOCK)  // 782

typedef __attribute__((ext_vector_type(8))) short short8;
typedef __attribute__((ext_vector_type(4))) float f32x4;

// ---- ws layout ----
// [0    .. 256)   : logw, 64 floats
// [256  .. 6512)  : per-block double partials (NBLOCKS * 8)
// [8192 .. +256K) : bstage, frag-ordered B. short-index:
//                   kb*4096 + h*2048 + ct*512 + (g*16+c)*8 + kk
//                   = bf16(h=0:hi,1:lo) of log(otu[ct*16+c][kb*32+g*8+kk]+eps)
#define WS_LOGW      0
#define WS_PARTIALS  256
#define WS_BSTAGE    8192

__device__ __forceinline__ unsigned short f32_bf16_rn(float f) {
  unsigned int u = __float_as_uint(f);
  unsigned int r = u + 0x7fffu + ((u >> 16) & 1u);
  return (unsigned short)(r >> 16);
}

__global__ void prep_kernel(const float* __restrict__ otu,
                            const float* __restrict__ comm,
                            unsigned short* __restrict__ bstage,
                            float* __restrict__ logw) {
  int b = blockIdx.x;
  if (b < KC) {
    int c = b & 15, ct = b >> 4;
    for (int k = threadIdx.x; k < OD; k += blockDim.x) {
      float x = logf(otu[b * OD + k] + EPSF);
      unsigned short h = f32_bf16_rn(x);
      float hf = __uint_as_float(((unsigned int)h) << 16);
      unsigned short l = f32_bf16_rn(x - hf);
      int kb = k >> 5, g = (k >> 3) & 3, kk = k & 7;
      size_t base = (size_t)kb * 4096 + (size_t)ct * 512
                  + (size_t)(g * 16 + c) * 8 + kk;
      bstage[base] = h;           // hi
      bstage[base + 2048] = l;    // lo
    }
  } else {
    if (threadIdx.x < KC) logw[threadIdx.x] = logf(comm[threadIdx.x] + EPSF);
  }
}

// 4 waves * 32 rows = 128 rows/block, all 64 community cols per wave.
// No LDS, no barriers: B frags come straight from L2-resident bstage.
// A is read in K-chunks of 256: per chunk the wave issues all 32 float4
// loads back-to-back (1 KB contiguous per row per visit), packs to bf16
// (exact for integer counts), then 128 MFMAs. Chunk phase rotates per block
// so column offsets spread across channels GPU-wide.
__global__ __launch_bounds__(256, 2)
void ll_kernel(const float* __restrict__ counts,
               const unsigned short* __restrict__ bstage,
               const float* __restrict__ logw,
               double* __restrict__ partials) {
  const int tid = threadIdx.x;
  const int wave = tid >> 6;
  const int lane = tid & 63;
  const int g = lane >> 4;   // k-group within frag
  const int c = lane & 15;   // A-row / B-col within 16-tile
  const int rowBase = blockIdx.x * ROWS_PER_BLOCK + wave * 32;

  f32x4 acc[2][4];
#pragma unroll
  for (int i = 0; i < 2; ++i)
#pragma unroll
    for (int j = 0; j < 4; ++j)
      acc[i][j] = (f32x4){0.f, 0.f, 0.f, 0.f};

  int r0 = rowBase + c;      if (r0 >= NP) r0 = NP - 1;  // tail rows dropped in epilogue
  int r1 = rowBase + 16 + c; if (r1 >= NP) r1 = NP - 1;
  const float* pa0 = counts + (size_t)r0 * OD + g * 8;
  const float* pa1 = counts + (size_t)r1 * OD + g * 8;

  const int p = blockIdx.x & 3;   // chunk-phase rotation

  for (int ci = 0; ci < 4; ++ci) {
    const int t = (p + ci) & 3;            // K-chunk: cols [t*256, t*256+256)
    const float* a0 = pa0 + t * 256;
    const float* a1 = pa1 + t * 256;

    // 1) burst-issue all 32 A loads (1 KB contiguous per row per visit)
    float4 x0[8], x1[8], y0[8], y1[8];
#pragma unroll
    for (int s = 0; s < 8; ++s) {
      x0[s] = *(const float4*)(a0 + s * 32);
      x1[s] = *(const float4*)(a0 + s * 32 + 4);
      y0[s] = *(const float4*)(a1 + s * 32);
      y1[s] = *(const float4*)(a1 + s * 32 + 4);
    }

    // 2) pack to bf16 (truncation; exact for integer counts)
    short8 ah0[8], ah1[8];
#pragma unroll
    for (int s = 0; s < 8; ++s) {
      union { unsigned int u[4]; short8 v; } u0, u1;
      u0.u[0] = __builtin_amdgcn_perm(__float_as_uint(x0[s].y), __float_as_uint(x0[s].x), 0x07060302u);
      u0.u[1] = __builtin_amdgcn_perm(__float_as_uint(x0[s].w), __float_as_uint(x0[s].z), 0x07060302u);
      u0.u[2] = __builtin_amdgcn_perm(__float_as_uint(x1[s].y), __float_as_uint(x1[s].x), 0x07060302u);
      u0.u[3] = __builtin_amdgcn_perm(__float_as_uint(x1[s].w), __float_as_uint(x1[s].z), 0x07060302u);
      u1.u[0] = __builtin_amdgcn_perm(__float_as_uint(y0[s].y), __float_as_uint(y0[s].x), 0x07060302u);
      u1.u[1] = __builtin_amdgcn_perm(__float_as_uint(y0[s].w), __float_as_uint(y0[s].z), 0x07060302u);
      u1.u[2] = __builtin_amdgcn_perm(__float_as_uint(y1[s].y), __float_as_uint(y1[s].x), 0x07060302u);
      u1.u[3] = __builtin_amdgcn_perm(__float_as_uint(y1[s].w), __float_as_uint(y1[s].z), 0x07060302u);
      ah0[s] = u0.v;
      ah1[s] = u1.v;
    }

    // 3) compute: per 32-k sub-step, B frags from L2 + 16 MFMA
#pragma unroll
    for (int s = 0; s < 8; ++s) {
      const int kb = t * 8 + s;
      const unsigned short* bb = bstage + (size_t)kb * 4096 + (size_t)lane * 8;
      short8 fbh[4], fbl[4];
#pragma unroll
      for (int ct = 0; ct < 4; ++ct) {
        fbh[ct] = *(const short8*)(bb + ct * 512);
        fbl[ct] = *(const short8*)(bb + 2048 + ct * 512);
      }
#pragma unroll
      for (int ct = 0; ct < 4; ++ct) {
        acc[0][ct] = __builtin_amdgcn_mfma_f32_16x16x32_bf16(ah0[s], fbh[ct], acc[0][ct], 0, 0, 0);
        acc[1][ct] = __builtin_amdgcn_mfma_f32_16x16x32_bf16(ah1[s], fbh[ct], acc[1][ct], 0, 0, 0);
        acc[0][ct] = __builtin_amdgcn_mfma_f32_16x16x32_bf16(ah0[s], fbl[ct], acc[0][ct], 0, 0, 0);
        acc[1][ct] = __builtin_amdgcn_mfma_f32_16x16x32_bf16(ah1[s], fbl[ct], acc[1][ct], 0, 0, 0);
      }
    }
  }

  // ---- epilogue: + logw, logsumexp over 64 cols per row, accumulate rows ----
  float lw[4];
#pragma unroll
  for (int ct = 0; ct < 4; ++ct) lw[ct] = logw[ct * 16 + c];

  double lsum = 0.0;
#pragma unroll
  for (int rt = 0; rt < 2; ++rt) {
#pragma unroll
    for (int r = 0; r < 4; ++r) {
      // lane holds cols {ct*16+c}, row = rowBase + rt*16 + g*4 + r
      float v0 = acc[rt][0][r] + lw[0];
      float v1 = acc[rt][1][r] + lw[1];
      float v2 = acc[rt][2][r] + lw[2];
      float v3 = acc[rt][3][r] + lw[3];
      float m = fmaxf(fmaxf(v0, v1), fmaxf(v2, v3));
      m = fmaxf(m, __shfl_xor(m, 1));
      m = fmaxf(m, __shfl_xor(m, 2));
      m = fmaxf(m, __shfl_xor(m, 4));
      m = fmaxf(m, __shfl_xor(m, 8));
      float s = __expf(v0 - m) + __expf(v1 - m) + __expf(v2 - m) + __expf(v3 - m);
      s += __shfl_xor(s, 1);
      s += __shfl_xor(s, 2);
      s += __shfl_xor(s, 4);
      s += __shfl_xor(s, 8);
      float lse = m + __logf(s);
      int row = rowBase + rt * 16 + g * 4 + r;
      if (c == 0 && row < NP) lsum += (double)lse;
    }
  }
  lsum += __shfl_xor(lsum, 16);
  lsum += __shfl_xor(lsum, 32);

  __shared__ double wpart[4];
  if (lane == 0) wpart[wave] = lsum;
  __syncthreads();
  if (tid == 0) partials[blockIdx.x] = wpart[0] + wpart[1] + wpart[2] + wpart[3];
}

__global__ void finalize_kernel(const double* __restrict__ partials,
                                float* __restrict__ out) {
  double s = 0.0;
  for (int i = threadIdx.x; i < NBLOCKS; i += 256) s += partials[i];
  s += __shfl_xor(s, 1);
  s += __shfl_xor(s, 2);
  s += __shfl_xor(s, 4);
  s += __shfl_xor(s, 8);
  s += __shfl_xor(s, 16);
  s += __shfl_xor(s, 32);
  __shared__ double sp[4];
  int w = threadIdx.x >> 6, lane = threadIdx.x & 63;
  if (lane == 0) sp[w] = s;
  __syncthreads();
  if (threadIdx.x == 0) out[0] = (float)(sp[0] + sp[1] + sp[2] + sp[3]);
}

extern "C" void kernel_launch(void* const* d_in, const int* in_sizes, int n_in,
                              void* d_out, int out_size, void* d_ws, size_t ws_size,
                              hipStream_t stream) {
  const float* counts = (const float*)d_in[0];
  const float* otu    = (const float*)d_in[1];
  const float* comm   = (const float*)d_in[2];
  float* out = (float*)d_out;
  char* ws = (char*)d_ws;

  float* logw          = (float*)(ws + WS_LOGW);
  double* partials     = (double*)(ws + WS_PARTIALS);
  unsigned short* bst  = (unsigned short*)(ws + WS_BSTAGE);

  prep_kernel<<<KC + 1, 256, 0, stream>>>(otu, comm, bst, logw);
  ll_kernel<<<NBLOCKS, 256, 0, stream>>>(counts, bst, logw, partials);
  finalize_kernel<<<1, 256, 0, stream>>>(partials, out);
}